// Round 1
// baseline (6424.808 us; speedup 1.0000x reference)
//
#include <hip/hip_runtime.h>
#include <hip/hip_bf16.h>

#define NNODES 50000
#define DEG 16
#define DIN 963
#define DHID 256

#define BM 128
#define BN 64
#define BK 16

// ---------------- dual GEMM: ys = A@W1, yn = A@W2 (no bias) ----------------
// A: N x K row-major. W1,W2: K x 256 row-major. Grid: (ceil(N/BM), 512/BN).
__global__ __launch_bounds__(256) void gemm_dual(
    const float* __restrict__ A, int N, int K,
    const float* __restrict__ W1, const float* __restrict__ W2,
    float* __restrict__ ys, float* __restrict__ yn)
{
    __shared__ float As[BK][BM + 4];   // row stride 132 floats (16B aligned)
    __shared__ float Bs[BK][BN + 4];   // row stride 68 floats (16B aligned)

    const int bm = blockIdx.x * BM;
    const int bn = blockIdx.y * BN;          // 0..511 virtual cols
    const float* W = (bn < 256) ? W1 : W2;
    float* C       = (bn < 256) ? ys : yn;
    const int cn = bn & 255;

    const int tid = threadIdx.x;
    const int tx = tid & 15;    // 16 col groups (4 cols each)
    const int ty = tid >> 4;    // 16 row groups (8 rows each)

    float acc[8][4];
#pragma unroll
    for (int r = 0; r < 8; ++r)
#pragma unroll
        for (int c = 0; c < 4; ++c) acc[r][c] = 0.f;

    const int ktiles = (K + BK - 1) / BK;

    // A-load mapping: thread -> row m = tid>>1, k-range (tid&1)*8..+7
    const int am = tid >> 1;
    const int akb = (tid & 1) * 8;
    const int arow = bm + am;
    // B-load mapping: thread -> k row tid>>4, 4 cols at (tid&15)*4
    const int bk = tid >> 4;
    const int bn4 = (tid & 15) * 4;

    for (int kt = 0; kt < ktiles; ++kt) {
        const int k0 = kt * BK;
#pragma unroll
        for (int i = 0; i < 8; ++i) {
            const int k = k0 + akb + i;
            float v = 0.f;
            if (arow < N && k < K) v = A[(size_t)arow * K + k];
            As[akb + i][am] = v;
        }
        {
            const int gk = k0 + bk;
            float4 bv = make_float4(0.f, 0.f, 0.f, 0.f);
            if (gk < K) bv = *(const float4*)(W + (size_t)gk * 256 + cn + bn4);
            *(float4*)&Bs[bk][bn4] = bv;
        }
        __syncthreads();

#pragma unroll
        for (int kk = 0; kk < BK; ++kk) {
            float4 a0 = *(const float4*)&As[kk][ty * 8];
            float4 a1 = *(const float4*)&As[kk][ty * 8 + 4];
            float4 b0 = *(const float4*)&Bs[kk][tx * 4];
            float a[8] = {a0.x, a0.y, a0.z, a0.w, a1.x, a1.y, a1.z, a1.w};
            float b[4] = {b0.x, b0.y, b0.z, b0.w};
#pragma unroll
            for (int r = 0; r < 8; ++r)
#pragma unroll
                for (int c = 0; c < 4; ++c) acc[r][c] += a[r] * b[c];
        }
        __syncthreads();
    }

#pragma unroll
    for (int r = 0; r < 8; ++r) {
        const int row = bm + ty * 8 + r;
        if (row < N) {
            float4 v = make_float4(acc[r][0], acc[r][1], acc[r][2], acc[r][3]);
            *(float4*)&C[(size_t)row * 256 + cn + tx * 4] = v;
        }
    }
}

// ------------- combine: out = relu(ys + sum_j yn[nbr_j] + b); optional residual -------------
// one block (256 threads) per node row
__global__ __launch_bounds__(256) void combine_kernel(
    const float* __restrict__ ys, const float* __restrict__ yn,
    const int* __restrict__ nbr, const float* __restrict__ bias,
    const float* __restrict__ res, float* __restrict__ out, int N)
{
    const int n = blockIdx.x;
    const int c = threadIdx.x;

    __shared__ int nb[DEG];
    if (c < DEG) nb[c] = nbr[(size_t)n * DEG + c];
    __syncthreads();

    float s = ys[(size_t)n * 256 + c] + bias[c];
#pragma unroll
    for (int j = 0; j < DEG; ++j)
        s += yn[(size_t)nb[j] * 256 + c];
    s = fmaxf(s, 0.f);
    if (res != nullptr)
        s = (res[(size_t)n * 256 + c] + s) * 0.5f;
    out[(size_t)n * 256 + c] = s;
}

// ------------- coords head: out3 = x @ We (256x3) + be -------------
// one wave (64 threads) per node row
__global__ __launch_bounds__(64) void coords_kernel(
    const float* __restrict__ x, const float* __restrict__ We,
    const float* __restrict__ be, float* __restrict__ out3, int N)
{
    const int n = blockIdx.x;
    const int l = threadIdx.x;
    const float4 xv = *(const float4*)(x + (size_t)n * 256 + l * 4);
    float p0 = 0.f, p1 = 0.f, p2 = 0.f;
    const float xs[4] = {xv.x, xv.y, xv.z, xv.w};
#pragma unroll
    for (int i = 0; i < 4; ++i) {
        const int cidx = l * 4 + i;
        p0 += xs[i] * We[cidx * 3 + 0];
        p1 += xs[i] * We[cidx * 3 + 1];
        p2 += xs[i] * We[cidx * 3 + 2];
    }
#pragma unroll
    for (int off = 32; off > 0; off >>= 1) {
        p0 += __shfl_down(p0, off);
        p1 += __shfl_down(p1, off);
        p2 += __shfl_down(p2, off);
    }
    if (l == 0) {
        out3[(size_t)n * 3 + 0] = p0 + be[0];
        out3[(size_t)n * 3 + 1] = p1 + be[1];
        out3[(size_t)n * 3 + 2] = p2 + be[2];
    }
}

extern "C" void kernel_launch(void* const* d_in, const int* in_sizes, int n_in,
                              void* d_out, int out_size, void* d_ws, size_t ws_size,
                              hipStream_t stream) {
    const int N = NNODES;
    const int* nbr   = (const int*)d_in[0];
    const float* sf  = (const float*)d_in[1];
    const float* Ws0 = (const float*)d_in[2];
    const float* Wn0 = (const float*)d_in[3];
    const float* b0  = (const float*)d_in[4];
    const float* Ws  = (const float*)d_in[5];   // 13 x 256 x 256
    const float* Wn  = (const float*)d_in[6];
    const float* bb  = (const float*)d_in[7];   // 13 x 256
    const float* We  = (const float*)d_in[8];   // 256 x 3
    const float* be  = (const float*)d_in[9];   // 3

    float* out   = (float*)d_out;               // x: N*256 then coords: N*3
    float* P  = (float*)d_ws;                   // N*256
    float* Q  = P + (size_t)N * 256;            // N*256
    float* yn = Q + (size_t)N * 256;            // N*256
    float* ys = out;                            // reuse d_out x-region as ys scratch

    const dim3 gemmGrid((N + BM - 1) / BM, 512 / BN);
    const dim3 gemmBlk(256);

    // Layer 0: K = 963
    gemm_dual<<<gemmGrid, gemmBlk, 0, stream>>>(sf, N, DIN, Ws0, Wn0, ys, yn);
    combine_kernel<<<N, 256, 0, stream>>>(ys, yn, nbr, b0, nullptr, P, N);

    // 6 residual blocks of 2 layers each (layer idx 0..11)
    for (int blk = 0; blk < 6; ++blk) {
        const int lA = 2 * blk;
        const int lB = 2 * blk + 1;
        // layer A: P -> Q
        gemm_dual<<<gemmGrid, gemmBlk, 0, stream>>>(P, N, DHID,
            Ws + (size_t)lA * 65536, Wn + (size_t)lA * 65536, ys, yn);
        combine_kernel<<<N, 256, 0, stream>>>(ys, yn, nbr, bb + lA * 256, nullptr, Q, N);
        // layer B: Q -> P, residual with temp=P, in-place
        gemm_dual<<<gemmGrid, gemmBlk, 0, stream>>>(Q, N, DHID,
            Ws + (size_t)lB * 65536, Wn + (size_t)lB * 65536, ys, yn);
        combine_kernel<<<N, 256, 0, stream>>>(ys, yn, nbr, bb + lB * 256, P, P, N);
    }

    // Layer 12: P -> d_out (x), no residual. ys==out: in-place per-element OK.
    gemm_dual<<<gemmGrid, gemmBlk, 0, stream>>>(P, N, DHID,
        Ws + (size_t)12 * 65536, Wn + (size_t)12 * 65536, ys, yn);
    combine_kernel<<<N, 256, 0, stream>>>(ys, yn, nbr, bb + 12 * 256, nullptr, out, N);

    // coords head
    coords_kernel<<<N, 64, 0, stream>>>(out, We, be, out + (size_t)N * 256, N);
}

// Round 2
// 1633.327 us; speedup vs baseline: 3.9336x; 3.9336x over previous
//
#include <hip/hip_runtime.h>
#include <hip/hip_bf16.h>
#include <hip/hip_fp16.h>
#include <stdint.h>

#define NNODES 50000
#define NPAD   50048          // 391 * 128
#define DEG    16
#define DIN    963
#define K0PAD  992            // 31 * 32
#define DHID   256
#define SCALE  (1.0f / 1024.0f)
#define ISCALE 1024.0f

typedef __attribute__((ext_vector_type(4))) float    f32x4;
typedef __attribute__((ext_vector_type(8))) _Float16 f16x8;
typedef __attribute__((ext_vector_type(4))) _Float16 f16x4;

typedef const __attribute__((address_space(1))) void GV;
typedef __attribute__((address_space(3))) void LV;

__device__ __forceinline__ void gl2lds16(const void* g, void* l) {
    __builtin_amdgcn_global_load_lds((GV*)g, (LV*)l, 16, 0, 0);
}

// ---------------- MFMA dual GEMM ----------------
// A: [NPAD][K] fp16 row-major (K % 32 == 0). Wp: [512][K] fp16 (pre-transposed weights:
// Wp[n][k] = W[k][n], cols 0..255 = W_self, 256..511 = W_neigh).
// C: ys = A@Ws -> [NPAD][256], yn = A@Wn -> [NPAD][256], both fp16 (scaled domain).
// Grid: (NPAD/128, 4). 256 threads = 4 waves, wave tile 64x64, mfma 16x16x32 f16.
__global__ __launch_bounds__(256) void gemm_mfma(
    const _Float16* __restrict__ A, int K,
    const _Float16* __restrict__ Wp,
    _Float16* __restrict__ ys, _Float16* __restrict__ yn)
{
    // LDS tile layout: [buf][A/B][kh(4)][row(128)][8] fp16 -> frag reads are
    // ds_read_b128 at 16B stride across lanes => bank-conflict-free.
    __shared__ _Float16 lds[2][2][4096];

    const int tid  = threadIdx.x;
    const int w    = tid >> 6;
    const int lane = tid & 63;
    const int bm   = blockIdx.x * 128;
    const int nb   = blockIdx.y * 128;       // 0..511 packed col base

    const int KT = K >> 5;

    auto stage = [&](int s, int kt) {
        const int k0 = kt << 5;
#pragma unroll
        for (int i = 0; i < 2; ++i) {
            const int j   = w + (i << 2);    // issue 0..7
            const int c   = (j << 6) + lane; // chunk 0..511 (16B each)
            const int row = c & 127;
            const int k8  = (c >> 7) << 3;   // k-half * 8
            gl2lds16(A  + (size_t)(bm + row) * K + k0 + k8, &lds[s][0][(size_t)j << 9]);
            gl2lds16(Wp + (size_t)(nb + row) * K + k0 + k8, &lds[s][1][(size_t)j << 9]);
        }
    };

    const int wm = (w >> 1) << 6;
    const int wn = (w & 1) << 6;
    const int lr = lane & 15;
    const int kh = lane >> 4;

    f32x4 acc[4][4] = {};

    stage(0, 0);
    __syncthreads();
    int cur = 0;
    for (int kt = 0; kt < KT; ++kt) {
        if (kt + 1 < KT) stage(cur ^ 1, kt + 1);
        f16x8 a[4], b[4];
#pragma unroll
        for (int mi = 0; mi < 4; ++mi)
            a[mi] = *(const f16x8*)&lds[cur][0][((kh << 7) + wm + (mi << 4) + lr) << 3];
#pragma unroll
        for (int ni = 0; ni < 4; ++ni)
            b[ni] = *(const f16x8*)&lds[cur][1][((kh << 7) + wn + (ni << 4) + lr) << 3];
#pragma unroll
        for (int mi = 0; mi < 4; ++mi)
#pragma unroll
            for (int ni = 0; ni < 4; ++ni)
                acc[mi][ni] = __builtin_amdgcn_mfma_f32_16x16x32_f16(a[mi], b[ni], acc[mi][ni], 0, 0, 0);
        __syncthreads();
        cur ^= 1;
    }

    // C/D layout: col = lane&15, row = (lane>>4)*4 + r  [measured m89/m91]
    _Float16* C = (blockIdx.y < 2) ? ys : yn;
    const int cb = (nb & 255) + wn;
#pragma unroll
    for (int mi = 0; mi < 4; ++mi) {
        const size_t rbase = (size_t)(bm + wm + (mi << 4) + (kh << 2)) << 8;
#pragma unroll
        for (int ni = 0; ni < 4; ++ni) {
            const int col = cb + (ni << 4) + lr;
#pragma unroll
            for (int r = 0; r < 4; ++r)
                C[rbase + ((size_t)r << 8) + col] = (_Float16)acc[mi][ni][r];
        }
    }
}

// ------------- combine: x = relu(ys + sum_j yn[nbr_j] + b*SCALE); optional residual -------------
__global__ __launch_bounds__(256) void combine(
    const _Float16* __restrict__ ys, const _Float16* __restrict__ yn,
    const int* __restrict__ nbr, const float* __restrict__ bias,
    const _Float16* __restrict__ res,
    _Float16* __restrict__ outh, float* __restrict__ outf)
{
    const int n = blockIdx.x;
    const int c = threadIdx.x;
    __shared__ int nb[DEG];
    if (c < DEG) nb[c] = nbr[n * DEG + c];
    __syncthreads();
    float s = (float)ys[((size_t)n << 8) + c] + bias[c] * SCALE;
#pragma unroll
    for (int j = 0; j < DEG; ++j)
        s += (float)yn[((size_t)nb[j] << 8) + c];
    s = fmaxf(s, 0.f);
    if (res) s = ((float)res[((size_t)n << 8) + c] + s) * 0.5f;
    if (outh) outh[((size_t)n << 8) + c] = (_Float16)s;
    else      outf[((size_t)n << 8) + c] = s * ISCALE;   // final layer: unscale to fp32
}

// ------------- coords head: out3 = x @ We (256x3) + be (fp32, unscaled) -------------
__global__ __launch_bounds__(64) void coords_kernel(
    const float* __restrict__ x, const float* __restrict__ We,
    const float* __restrict__ be, float* __restrict__ out3, int N)
{
    const int n = blockIdx.x;
    const int l = threadIdx.x;
    const float4 xv = *(const float4*)(x + (size_t)n * 256 + l * 4);
    float p0 = 0.f, p1 = 0.f, p2 = 0.f;
    const float xs[4] = {xv.x, xv.y, xv.z, xv.w};
#pragma unroll
    for (int i = 0; i < 4; ++i) {
        const int cidx = l * 4 + i;
        p0 += xs[i] * We[cidx * 3 + 0];
        p1 += xs[i] * We[cidx * 3 + 1];
        p2 += xs[i] * We[cidx * 3 + 2];
    }
#pragma unroll
    for (int off = 32; off > 0; off >>= 1) {
        p0 += __shfl_down(p0, off);
        p1 += __shfl_down(p1, off);
        p2 += __shfl_down(p2, off);
    }
    if (l == 0) {
        out3[(size_t)n * 3 + 0] = p0 + be[0];
        out3[(size_t)n * 3 + 1] = p1 + be[1];
        out3[(size_t)n * 3 + 2] = p2 + be[2];
    }
}

// ------------- conversion / packing kernels -------------
// sf [50000][963] f32 -> sfb [NPAD][992] fp16, scaled by 1/1024, zero-padded.
__global__ __launch_bounds__(256) void conv_sf(const float* __restrict__ sf,
                                               _Float16* __restrict__ sfb)
{
    const int idx = blockIdx.x * 256 + threadIdx.x;   // NPAD * 248 groups of 4
    const int row = idx / (K0PAD / 4);
    const int k4  = (idx % (K0PAD / 4)) * 4;
    f16x4 o;
#pragma unroll
    for (int i = 0; i < 4; ++i) {
        const int k = k4 + i;
        float v = (row < NNODES && k < DIN) ? sf[(size_t)row * DIN + k] * SCALE : 0.f;
        o[i] = (_Float16)v;
    }
    *(f16x4*)(sfb + (size_t)row * K0PAD + k4) = o;
}

// Ws0/Wn0 [963][256] f32 -> Wp0 [512][992] fp16 transposed+padded (unscaled).
__global__ __launch_bounds__(256) void pack_w0(const float* __restrict__ Ws0,
                                               const float* __restrict__ Wn0,
                                               _Float16* __restrict__ Wp0)
{
    const int idx = blockIdx.x * 256 + threadIdx.x;   // 512*992
    const int k  = idx >> 9;        // 0..991
    const int nn = idx & 511;       // coalesced reads over nn
    float v = 0.f;
    if (k < DIN) v = (nn < 256) ? Ws0[(size_t)k * 256 + nn]
                                : Wn0[(size_t)k * 256 + (nn - 256)];
    Wp0[(size_t)nn * K0PAD + k] = (_Float16)v;
}

// Ws/Wn [13][256][256] f32 -> Wpk [13][512][256] fp16 transposed (unscaled).
__global__ __launch_bounds__(256) void pack_w(const float* __restrict__ Ws,
                                              const float* __restrict__ Wn,
                                              _Float16* __restrict__ Wpk)
{
    const int idx = blockIdx.x * 256 + threadIdx.x;   // 13*512*256
    const int l   = idx >> 17;
    const int rem = idx & 131071;
    const int k   = rem >> 9;       // 0..255
    const int nn  = rem & 511;      // coalesced reads over nn
    const float v = (nn < 256) ? Ws[(size_t)l * 65536 + k * 256 + nn]
                               : Wn[(size_t)l * 65536 + k * 256 + (nn - 256)];
    Wpk[(size_t)l * 131072 + (size_t)nn * 256 + k] = (_Float16)v;
}

extern "C" void kernel_launch(void* const* d_in, const int* in_sizes, int n_in,
                              void* d_out, int out_size, void* d_ws, size_t ws_size,
                              hipStream_t stream)
{
    const int*   nbr = (const int*)d_in[0];
    const float* sf  = (const float*)d_in[1];
    const float* Ws0 = (const float*)d_in[2];
    const float* Wn0 = (const float*)d_in[3];
    const float* b0  = (const float*)d_in[4];
    const float* Ws  = (const float*)d_in[5];
    const float* Wn  = (const float*)d_in[6];
    const float* bb  = (const float*)d_in[7];
    const float* We  = (const float*)d_in[8];
    const float* be  = (const float*)d_in[9];
    float* out = (float*)d_out;

    // Workspace layout (151.6 MB total):
    //   [0, 99.3MB)   : sfb [NPAD][992] fp16   -- consumed by layer-0 GEMM, then reused:
    //                     P   = offset 0        [NPAD][256] fp16
    //                     Q   = offset 25.6MB   [NPAD][256] fp16
    //                     Wpk = offset 51.2MB   [13][512][256] fp16 (packed AFTER layer-0 GEMM)
    //   [99.3,100.3)  : Wp0 [512][992] fp16
    //   [100.3,125.9) : ysb [NPAD][256] fp16
    //   [125.9,151.6) : ynb [NPAD][256] fp16
    uint8_t* w = (uint8_t*)d_ws;
    _Float16* sfb = (_Float16*)w;
    _Float16* P   = (_Float16*)w;
    _Float16* Q   = P + (size_t)NPAD * 256;
    _Float16* Wpk = Q + (size_t)NPAD * 256;
    _Float16* Wp0 = (_Float16*)(w + (size_t)NPAD * K0PAD * 2);
    _Float16* ysb = Wp0 + (size_t)512 * K0PAD;
    _Float16* ynb = ysb + (size_t)NPAD * 256;

    conv_sf<<<NPAD * (K0PAD / 4) / 256, 256, 0, stream>>>(sf, sfb);
    pack_w0<<<512 * K0PAD / 256, 256, 0, stream>>>(Ws0, Wn0, Wp0);

    const dim3 gg(NPAD / 128, 4);

    // Layer 0 (K=992) — must complete before Wpk overwrites sfb's tail.
    gemm_mfma<<<gg, 256, 0, stream>>>(sfb, K0PAD, Wp0, ysb, ynb);
    pack_w<<<13 * 512 * 256 / 256, 256, 0, stream>>>(Ws, Wn, Wpk);
    combine<<<NNODES, 256, 0, stream>>>(ysb, ynb, nbr, b0, nullptr, P, nullptr);

    for (int t = 0; t < 6; ++t) {
        const int lA = 2 * t, lB = lA + 1;
        gemm_mfma<<<gg, 256, 0, stream>>>(P, 256, Wpk + (size_t)lA * 131072, ysb, ynb);
        combine<<<NNODES, 256, 0, stream>>>(ysb, ynb, nbr, bb + lA * 256, nullptr, Q, nullptr);
        gemm_mfma<<<gg, 256, 0, stream>>>(Q, 256, Wpk + (size_t)lB * 131072, ysb, ynb);
        combine<<<NNODES, 256, 0, stream>>>(ysb, ynb, nbr, bb + lB * 256, P, P, nullptr);
    }

    gemm_mfma<<<gg, 256, 0, stream>>>(P, 256, Wpk + (size_t)12 * 131072, ysb, ynb);
    combine<<<NNODES, 256, 0, stream>>>(ysb, ynb, nbr, bb + 12 * 256, nullptr, nullptr, out);

    coords_kernel<<<NNODES, 64, 0, stream>>>(out, We, be, out + (size_t)NNODES * 256, NNODES);
}

// Round 3
// 1598.824 us; speedup vs baseline: 4.0185x; 1.0216x over previous
//
#include <hip/hip_runtime.h>
#include <hip/hip_bf16.h>
#include <hip/hip_fp16.h>
#include <stdint.h>

#define NNODES 50000
#define NPAD   50048          // 391 * 128
#define DEG    16
#define DIN    963
#define K0PAD  992            // 31 * 32
#define DHID   256
#define SCALE  (1.0f / 1024.0f)
#define ISCALE 1024.0f

typedef __attribute__((ext_vector_type(4))) float    f32x4;
typedef __attribute__((ext_vector_type(8))) _Float16 f16x8;
typedef __attribute__((ext_vector_type(4))) _Float16 f16x4;

typedef const __attribute__((address_space(1))) void GV;
typedef __attribute__((address_space(3))) void LV;

__device__ __forceinline__ void gl2lds16(const void* g, void* l) {
    __builtin_amdgcn_global_load_lds((GV*)g, (LV*)l, 16, 0, 0);
}

// ---------------- MFMA dual GEMM, 8-wave 128x256 tile ----------------
// A: [NPAD][K] fp16 row-major (K % 32 == 0). Wp: [512][K] fp16 (pre-transposed:
// Wp[n][k] = W[k][n], cols 0..255 = W_self, 256..511 = W_neigh).
// Grid: 1-D, 782 blocks (391 row-tiles x 2 col-halves), 512 threads = 8 waves.
// Wave tile 64x64 (2M x 4N wave grid), mfma 16x16x32 f16.
__global__ __launch_bounds__(512) void gemm_mfma(
    const _Float16* __restrict__ A, int K,
    const _Float16* __restrict__ Wp,
    _Float16* __restrict__ ys, _Float16* __restrict__ yn)
{
    // LDS: kh-major [kh(4)][row][8] fp16 per buffer -> frag ds_read_b128 at 16B
    // lane stride = conflict-free (verified 0 conflicts in round 2).
    __shared__ _Float16 ldsA[2][4096];   // [kh][128][8] = 8KB/buf
    __shared__ _Float16 ldsB[2][8192];   // [kh][256][8] = 16KB/buf

    const int tid  = threadIdx.x;
    const int w    = tid >> 6;
    const int lane = tid & 63;

    // bijective XCD swizzle (m204): consecutive wgids -> same XCD, so the two
    // col-halves of a row-tile (wgid 2x, 2x+1) share the A-tile in one L2.
    const int nwg = gridDim.x;
    const int bid = blockIdx.x;
    const int q = nwg >> 3, r = nwg & 7, xc = bid & 7;
    const int wgid = (xc < r ? xc * (q + 1) : r * (q + 1) + (xc - r) * q) + (bid >> 3);
    const int bm = (wgid >> 1) << 7;
    const int by = wgid & 1;
    const int nb = by << 8;

    const int KT = K >> 5;

    auto stage = [&](int s, int kt) {
        const int k0 = kt << 5;
        {   // A: 512 chunks of 16B, 1 issue/thread. chunk c -> row=c&127, kh=c>>7
            const int c = (w << 6) + lane;
            gl2lds16(A + (size_t)(bm + (c & 127)) * K + k0 + ((c >> 7) << 3),
                     &ldsA[s][(size_t)w << 9]);
        }
#pragma unroll
        for (int i = 0; i < 2; ++i) {   // B: 1024 chunks, 2 issues/thread
            const int j = w + (i << 3);
            const int c = (j << 6) + lane;
            gl2lds16(Wp + (size_t)(nb + (c & 255)) * K + k0 + ((c >> 8) << 3),
                     &ldsB[s][(size_t)j << 9]);
        }
    };

    const int wm = (w >> 2) << 6;   // wave row offset (0/64)
    const int wn = (w & 3) << 6;    // wave col offset (0/64/128/192)
    const int lr = lane & 15;
    const int kh = lane >> 4;

    f32x4 acc[4][4] = {};

    stage(0, 0);
    __syncthreads();
    int cur = 0;
    for (int kt = 0; kt < KT; ++kt) {
        if (kt + 1 < KT) stage(cur ^ 1, kt + 1);
        f16x8 a[4], b[4];
#pragma unroll
        for (int mi = 0; mi < 4; ++mi)
            a[mi] = *(const f16x8*)&ldsA[cur][((kh << 7) + wm + (mi << 4) + lr) << 3];
#pragma unroll
        for (int ni = 0; ni < 4; ++ni)
            b[ni] = *(const f16x8*)&ldsB[cur][((kh << 8) + wn + (ni << 4) + lr) << 3];
#pragma unroll
        for (int mi = 0; mi < 4; ++mi)
#pragma unroll
            for (int ni = 0; ni < 4; ++ni)
                acc[mi][ni] = __builtin_amdgcn_mfma_f32_16x16x32_f16(a[mi], b[ni], acc[mi][ni], 0, 0, 0);
        __syncthreads();
        cur ^= 1;
    }

    // C/D layout: col = lane&15, row = (lane>>4)*4 + r  [measured m89/m91]
    _Float16* C = (by == 0) ? ys : yn;
#pragma unroll
    for (int mi = 0; mi < 4; ++mi) {
        const size_t rbase = (size_t)(bm + wm + (mi << 4) + (kh << 2)) << 8;
#pragma unroll
        for (int ni = 0; ni < 4; ++ni) {
            const int col = wn + (ni << 4) + lr;
#pragma unroll
            for (int r = 0; r < 4; ++r)
                C[rbase + ((size_t)r << 8) + col] = (_Float16)acc[mi][ni][r];
        }
    }
}

// ------------- combine: x = relu(ys + sum_j yn[nbr_j] + b*SCALE); optional residual -------
// one wave per node, f16x4 (8B/lane) vector loads for all gathers.
__global__ __launch_bounds__(256) void combine(
    const _Float16* __restrict__ ys, const _Float16* __restrict__ yn,
    const int* __restrict__ nbr, const float* __restrict__ bias,
    const _Float16* __restrict__ res,
    _Float16* __restrict__ outh, float* __restrict__ outf)
{
    const int w    = threadIdx.x >> 6;
    const int lane = threadIdx.x & 63;
    const int n    = (blockIdx.x << 2) + w;
    const int c4   = lane << 2;
    const size_t base = ((size_t)n << 8) + c4;

    const f16x4 ysv = *(const f16x4*)(ys + base);
    const float4 bv = *(const float4*)(bias + c4);
    float s0 = (float)ysv[0] + bv.x * SCALE;
    float s1 = (float)ysv[1] + bv.y * SCALE;
    float s2 = (float)ysv[2] + bv.z * SCALE;
    float s3 = (float)ysv[3] + bv.w * SCALE;

    const int* nr = nbr + n * DEG;
#pragma unroll
    for (int j = 0; j < DEG; ++j) {
        const f16x4 v = *(const f16x4*)(yn + (((size_t)nr[j]) << 8) + c4);
        s0 += (float)v[0]; s1 += (float)v[1]; s2 += (float)v[2]; s3 += (float)v[3];
    }
    s0 = fmaxf(s0, 0.f); s1 = fmaxf(s1, 0.f); s2 = fmaxf(s2, 0.f); s3 = fmaxf(s3, 0.f);
    if (res) {
        const f16x4 rv = *(const f16x4*)(res + base);
        s0 = ((float)rv[0] + s0) * 0.5f;
        s1 = ((float)rv[1] + s1) * 0.5f;
        s2 = ((float)rv[2] + s2) * 0.5f;
        s3 = ((float)rv[3] + s3) * 0.5f;
    }
    if (outh) {
        f16x4 o;
        o[0] = (_Float16)s0; o[1] = (_Float16)s1; o[2] = (_Float16)s2; o[3] = (_Float16)s3;
        *(f16x4*)(outh + base) = o;
    } else {
        float4 o = make_float4(s0 * ISCALE, s1 * ISCALE, s2 * ISCALE, s3 * ISCALE);
        *(float4*)(outf + base) = o;
    }
}

// ------------- coords head: out3 = x @ We (256x3) + be (fp32, unscaled) -------------
__global__ __launch_bounds__(64) void coords_kernel(
    const float* __restrict__ x, const float* __restrict__ We,
    const float* __restrict__ be, float* __restrict__ out3, int N)
{
    const int n = blockIdx.x;
    const int l = threadIdx.x;
    const float4 xv = *(const float4*)(x + (size_t)n * 256 + l * 4);
    float p0 = 0.f, p1 = 0.f, p2 = 0.f;
    const float xs[4] = {xv.x, xv.y, xv.z, xv.w};
#pragma unroll
    for (int i = 0; i < 4; ++i) {
        const int cidx = l * 4 + i;
        p0 += xs[i] * We[cidx * 3 + 0];
        p1 += xs[i] * We[cidx * 3 + 1];
        p2 += xs[i] * We[cidx * 3 + 2];
    }
#pragma unroll
    for (int off = 32; off > 0; off >>= 1) {
        p0 += __shfl_down(p0, off);
        p1 += __shfl_down(p1, off);
        p2 += __shfl_down(p2, off);
    }
    if (l == 0) {
        out3[(size_t)n * 3 + 0] = p0 + be[0];
        out3[(size_t)n * 3 + 1] = p1 + be[1];
        out3[(size_t)n * 3 + 2] = p2 + be[2];
    }
}

// ------------- conversion / packing kernels -------------
// sf [50000][963] f32 -> sfb [NPAD][992] fp16, scaled by 1/1024, zero-padded.
__global__ __launch_bounds__(256) void conv_sf(const float* __restrict__ sf,
                                               _Float16* __restrict__ sfb)
{
    const int idx = blockIdx.x * 256 + threadIdx.x;   // NPAD * 124
    const int row = idx / 124;
    const int k8  = (idx % 124) << 3;
    f16x8 o = {};
    if (row < NNODES) {
#pragma unroll
        for (int i = 0; i < 8; ++i) {
            const int k = k8 + i;
            o[i] = (k < DIN) ? (_Float16)(sf[(size_t)row * DIN + k] * SCALE) : (_Float16)0.f;
        }
    }
    *(f16x8*)(sfb + (size_t)row * K0PAD + k8) = o;
}

// Ws0/Wn0 [963][256] f32 -> Wp0 [512][992] fp16 transposed+padded (unscaled).
__global__ __launch_bounds__(256) void pack_w0(const float* __restrict__ Ws0,
                                               const float* __restrict__ Wn0,
                                               _Float16* __restrict__ Wp0)
{
    const int idx = blockIdx.x * 256 + threadIdx.x;   // 512 * 124
    const int nn  = idx & 511;       // coalesced reads across nn
    const int k8  = idx >> 9;        // 0..123
    const float* W = (nn < 256) ? Ws0 : Wn0;
    const int n0 = nn & 255;
    f16x8 o;
#pragma unroll
    for (int i = 0; i < 8; ++i) {
        const int k = (k8 << 3) + i;
        o[i] = (k < DIN) ? (_Float16)W[(size_t)k * 256 + n0] : (_Float16)0.f;
    }
    *(f16x8*)(Wp0 + (size_t)nn * K0PAD + (k8 << 3)) = o;
}

// Ws/Wn [13][256][256] f32 -> Wpk [13][512][256] fp16 transposed (unscaled).
__global__ __launch_bounds__(256) void pack_w(const float* __restrict__ Ws,
                                              const float* __restrict__ Wn,
                                              _Float16* __restrict__ Wpk)
{
    const int idx = blockIdx.x * 256 + threadIdx.x;   // 13*512*32
    const int nn  = idx & 511;
    const int k8  = (idx >> 9) & 31;
    const int l   = idx >> 14;
    const float* W = (nn < 256) ? Ws : Wn;
    const int n0 = nn & 255;
    f16x8 o;
#pragma unroll
    for (int i = 0; i < 8; ++i)
        o[i] = (_Float16)W[(size_t)l * 65536 + ((k8 << 3) + i) * 256 + n0];
    *(f16x8*)(Wpk + (size_t)l * 131072 + (size_t)nn * 256 + (k8 << 3)) = o;
}

extern "C" void kernel_launch(void* const* d_in, const int* in_sizes, int n_in,
                              void* d_out, int out_size, void* d_ws, size_t ws_size,
                              hipStream_t stream)
{
    const int*   nbr = (const int*)d_in[0];
    const float* sf  = (const float*)d_in[1];
    const float* Ws0 = (const float*)d_in[2];
    const float* Wn0 = (const float*)d_in[3];
    const float* b0  = (const float*)d_in[4];
    const float* Ws  = (const float*)d_in[5];
    const float* Wn  = (const float*)d_in[6];
    const float* bb  = (const float*)d_in[7];
    const float* We  = (const float*)d_in[8];
    const float* be  = (const float*)d_in[9];
    float* out = (float*)d_out;

    // Workspace layout (151.6 MB):
    //   [0, 99.3MB)   : sfb [NPAD][992] fp16 -- consumed by layer-0 GEMM, then reused:
    //                     P = offset 0, Q = +25.6MB, Wpk = +51.2MB (packed AFTER layer-0 GEMM)
    //   [99.3,100.3)  : Wp0 [512][992] fp16
    //   [100.3,125.9) : ysb [NPAD][256] fp16
    //   [125.9,151.6) : ynb [NPAD][256] fp16
    uint8_t* w = (uint8_t*)d_ws;
    _Float16* sfb = (_Float16*)w;
    _Float16* P   = (_Float16*)w;
    _Float16* Q   = P + (size_t)NPAD * 256;
    _Float16* Wpk = Q + (size_t)NPAD * 256;
    _Float16* Wp0 = (_Float16*)(w + (size_t)NPAD * K0PAD * 2);
    _Float16* ysb = Wp0 + (size_t)512 * K0PAD;
    _Float16* ynb = ysb + (size_t)NPAD * 256;

    conv_sf<<<NPAD * 124 / 256, 256, 0, stream>>>(sf, sfb);
    pack_w0<<<512 * 124 / 256, 256, 0, stream>>>(Ws0, Wn0, Wp0);

    const int gemmGrid = (NPAD / 128) * 2;   // 782

    // Layer 0 (K=992) — must complete before Wpk overwrites sfb's tail.
    gemm_mfma<<<gemmGrid, 512, 0, stream>>>(sfb, K0PAD, Wp0, ysb, ynb);
    pack_w<<<13 * 512 * 32 / 256, 256, 0, stream>>>(Ws, Wn, Wpk);
    combine<<<NNODES / 4, 256, 0, stream>>>(ysb, ynb, nbr, b0, nullptr, P, nullptr);

    for (int t = 0; t < 6; ++t) {
        const int lA = 2 * t, lB = lA + 1;
        gemm_mfma<<<gemmGrid, 512, 0, stream>>>(P, 256, Wpk + (size_t)lA * 131072, ysb, ynb);
        combine<<<NNODES / 4, 256, 0, stream>>>(ysb, ynb, nbr, bb + lA * 256, nullptr, Q, nullptr);
        gemm_mfma<<<gemmGrid, 512, 0, stream>>>(Q, 256, Wpk + (size_t)lB * 131072, ysb, ynb);
        combine<<<NNODES / 4, 256, 0, stream>>>(ysb, ynb, nbr, bb + lB * 256, P, P, nullptr);
    }

    gemm_mfma<<<gemmGrid, 512, 0, stream>>>(P, 256, Wpk + (size_t)12 * 131072, ysb, ynb);
    combine<<<NNODES / 4, 256, 0, stream>>>(ysb, ynb, nbr, bb + 12 * 256, nullptr, nullptr, out);

    coords_kernel<<<NNODES, 64, 0, stream>>>(out, We, be, out + (size_t)NNODES * 256, NNODES);
}